// Round 1
// baseline (1404.007 us; speedup 1.0000x reference)
//
#include <hip/hip_runtime.h>

// Relation-aware MHA, MI355X/gfx950.
// Pipeline: split f32->bf16(hi,lo) -> QKV proj GEMM (MFMA, split) -> fused attention
// (QK^T + q·relations_k, exp (no-max), PV + P·relations_v, E/l for weights_avg)
// -> combine/normalize -> O-proj GEMM -> P_avg kernel.

typedef unsigned short u16;
typedef __attribute__((ext_vector_type(8))) short bf16x8;   // 8 bf16 (4 VGPRs)
typedef __attribute__((ext_vector_type(4))) float f32x4;    // MFMA accumulator

#define MFMA16(a, b, c) __builtin_amdgcn_mfma_f32_16x16x32_bf16(a, b, c, 0, 0, 0)

__device__ __forceinline__ u16 f2bf(float f) {
  unsigned int u = __float_as_uint(f);
  u += 0x7fffu + ((u >> 16) & 1u);   // RNE
  return (u16)(u >> 16);
}
__device__ __forceinline__ float bf2f(u16 s) {
  return __uint_as_float(((unsigned int)s) << 16);
}
__device__ __forceinline__ void split2(float f, u16 &h, u16 &l) {
  h = f2bf(f);
  l = f2bf(f - bf2f(h));
}
__device__ __forceinline__ void cvt8(const float4 f0, const float4 f1, bf16x8 &bh, bf16x8 &bl) {
  u16 h, l;
  split2(f0.x, h, l); bh[0] = (short)h; bl[0] = (short)l;
  split2(f0.y, h, l); bh[1] = (short)h; bl[1] = (short)l;
  split2(f0.z, h, l); bh[2] = (short)h; bl[2] = (short)l;
  split2(f0.w, h, l); bh[3] = (short)h; bl[3] = (short)l;
  split2(f1.x, h, l); bh[4] = (short)h; bl[4] = (short)l;
  split2(f1.y, h, l); bh[5] = (short)h; bl[5] = (short)l;
  split2(f1.z, h, l); bh[6] = (short)h; bl[6] = (short)l;
  split2(f1.w, h, l); bh[7] = (short)h; bl[7] = (short)l;
}

// ---------------------------------------------------------------------------
// 1) split f32 -> bf16 hi/lo for activations (query,key,value) and 4 weights
// ---------------------------------------------------------------------------
__global__ __launch_bounds__(256) void k_split(
    const float* __restrict__ s0, const float* __restrict__ s1, const float* __restrict__ s2,
    const float* __restrict__ s3, const float* __restrict__ s4, const float* __restrict__ s5,
    const float* __restrict__ s6,
    u16* __restrict__ Xhi, u16* __restrict__ Xlo,
    u16* __restrict__ Whi, u16* __restrict__ Wlo)
{
  const int z = blockIdx.y;
  const float* src; u16 *dh, *dl; int n;
  if (z < 3) {
    src = (z == 0) ? s0 : ((z == 1) ? s1 : s2);
    dh = Xhi + (size_t)z * 2097152; dl = Xlo + (size_t)z * 2097152; n = 2097152;
  } else {
    int v = z - 3;
    src = (v == 0) ? s3 : ((v == 1) ? s4 : ((v == 2) ? s5 : s6));
    dh = Whi + (size_t)v * 1048576; dl = Wlo + (size_t)v * 1048576; n = 1048576;
  }
  int idx = (int)(blockIdx.x * 256 + threadIdx.x) * 4;
  if (idx >= n) return;
  float4 f = *(const float4*)(src + idx);
  ushort4 H, L; u16 h, l;
  split2(f.x, h, l); H.x = h; L.x = l;
  split2(f.y, h, l); H.y = h; L.y = l;
  split2(f.z, h, l); H.z = h; L.z = l;
  split2(f.w, h, l); H.w = h; L.w = l;
  *(ushort4*)(dh + idx) = H;
  *(ushort4*)(dl + idx) = L;
}

// ---------------------------------------------------------------------------
// 2) split-precision GEMM  Y = X @ W^T (+bias)  via K'=3K plain bf16 MFMA
//    MODE 0: z=0 Q (scaled, split-out [b][h][s][d]); z=1 K (split-out);
//            z=2 V (transposed out [b][h][d][s], split)
//    MODE 1: O-proj, f32 out to d_out
// ---------------------------------------------------------------------------
template<int MODE>
__global__ __launch_bounds__(256) void k_gemm(
    const u16* __restrict__ Ah0, const u16* __restrict__ Al0,
    const u16* __restrict__ Bh0, const u16* __restrict__ Bl0,
    const float* __restrict__ bias_q, const float* __restrict__ bias_k, const float* __restrict__ bias_v,
    u16* __restrict__ Qhi, u16* __restrict__ Qlo,
    u16* __restrict__ Khi, u16* __restrict__ Klo,
    u16* __restrict__ Vth, u16* __restrict__ Vtl,
    float* __restrict__ of32)
{
  const int z = blockIdx.z;
  const u16* Ah = Ah0 + (size_t)z * 2097152;
  const u16* Al = Al0 + (size_t)z * 2097152;
  const u16* Bh = Bh0 + (size_t)z * 1048576;
  const u16* Bl = Bl0 + (size_t)z * 1048576;
  const int m0 = blockIdx.x * 128, n0 = blockIdx.y * 128;
  const int t = threadIdx.x, lane = t & 63, w = t >> 6;
  const int wr = w >> 1, wc = w & 1;
  const int srow = t >> 2, scol = (t & 3) * 8;

  __shared__ __align__(16) u16 lsA[2][128 * 40];  // 32 k + 8 pad (bank spread)
  __shared__ __align__(16) u16 lsB[2][128 * 40];

  uint4 ra0, ra1, rb0, rb1;
#define GLOAD(s) { int seg = (s) >> 5; int ka = ((s) & 31) * 32 + scol;              \
    const u16* As = (seg < 2) ? Ah : Al;                                             \
    const u16* Bs = (seg == 1) ? Bl : Bh;                                            \
    ra0 = *(const uint4*)(As + (size_t)(m0 + srow) * 1024 + ka);                     \
    ra1 = *(const uint4*)(As + (size_t)(m0 + 64 + srow) * 1024 + ka);                \
    rb0 = *(const uint4*)(Bs + (size_t)(n0 + srow) * 1024 + ka);                     \
    rb1 = *(const uint4*)(Bs + (size_t)(n0 + 64 + srow) * 1024 + ka); }
#define LSTORE(bi) { *(uint4*)&lsA[bi][srow * 40 + scol] = ra0;                      \
    *(uint4*)&lsA[bi][(64 + srow) * 40 + scol] = ra1;                                \
    *(uint4*)&lsB[bi][srow * 40 + scol] = rb0;                                       \
    *(uint4*)&lsB[bi][(64 + srow) * 40 + scol] = rb1; }

  f32x4 acc[4][4];
#pragma unroll
  for (int i = 0; i < 4; ++i)
#pragma unroll
    for (int j = 0; j < 4; ++j) acc[i][j] = (f32x4){0.f, 0.f, 0.f, 0.f};

  GLOAD(0); LSTORE(0); GLOAD(1);
  const int ra = lane & 15, rc = 8 * (lane >> 4);
  for (int s = 0; s < 96; ++s) {
    __syncthreads();
    if (s + 1 < 96) LSTORE((s + 1) & 1);
    const int bi = s & 1;
    bf16x8 afr[4], bfr[4];
#pragma unroll
    for (int i = 0; i < 4; ++i) afr[i] = *(const bf16x8*)&lsA[bi][(wr * 64 + i * 16 + ra) * 40 + rc];
#pragma unroll
    for (int j = 0; j < 4; ++j) bfr[j] = *(const bf16x8*)&lsB[bi][(wc * 64 + j * 16 + ra) * 40 + rc];
#pragma unroll
    for (int i = 0; i < 4; ++i)
#pragma unroll
      for (int j = 0; j < 4; ++j) acc[i][j] = MFMA16(afr[i], bfr[j], acc[i][j]);
    if (s + 2 < 96) GLOAD(s + 2);
  }
#undef GLOAD
#undef LSTORE

#pragma unroll
  for (int i = 0; i < 4; ++i) {
#pragma unroll
    for (int j = 0; j < 4; ++j) {
      const int row0 = m0 + wr * 64 + i * 16 + (lane >> 4) * 4;   // n index (4 consecutive rows)
      const int col  = n0 + wc * 64 + j * 16 + (lane & 15);       // e index
      if (MODE == 0) {
        const float* bias = (z == 0) ? bias_q : ((z == 1) ? bias_k : bias_v);
        const float bv = bias[col];
        const int bb = row0 >> 10, s0i = row0 & 1023, hh = col >> 6, dd = col & 63;
        if (z == 2) {
          ushort4 HV, LV; u16 xh, xl;
          float v0 = acc[i][j][0] + bv; split2(v0, xh, xl); HV.x = xh; LV.x = xl;
          float v1 = acc[i][j][1] + bv; split2(v1, xh, xl); HV.y = xh; LV.y = xl;
          float v2 = acc[i][j][2] + bv; split2(v2, xh, xl); HV.z = xh; LV.z = xl;
          float v3 = acc[i][j][3] + bv; split2(v3, xh, xl); HV.w = xh; LV.w = xl;
          size_t base = ((size_t)(bb * 16 + hh) * 64 + dd) * 1024 + s0i;
          *(ushort4*)(Vth + base) = HV;
          *(ushort4*)(Vtl + base) = LV;
        } else {
          u16* dh = (z == 0) ? Qhi : Khi;
          u16* dl = (z == 0) ? Qlo : Klo;
          size_t base = (size_t)(bb * 16 + hh) * 65536 + dd;
#pragma unroll
          for (int r = 0; r < 4; ++r) {
            float v = acc[i][j][r] + bv;
            if (z == 0) v *= 0.125f;   // SCALING = 64^-0.5
            u16 xh, xl; split2(v, xh, xl);
            dh[base + (size_t)(s0i + r) * 64] = xh;
            dl[base + (size_t)(s0i + r) * 64] = xl;
          }
        }
      } else {
        const float bv = bias_q[col];
#pragma unroll
        for (int r = 0; r < 4; ++r)
          of32[(size_t)(row0 + r) * 1024 + col] = acc[i][j][r] + bv;
      }
    }
  }
}

// ---------------------------------------------------------------------------
// 3) fused attention. WG = (b, 16-query tile, k-half). 512 threads (8 waves).
// ---------------------------------------------------------------------------
__global__ __launch_bounds__(512) void k_attn(
    const u16* __restrict__ Qh, const u16* __restrict__ Ql,
    const u16* __restrict__ Kh, const u16* __restrict__ Kl,
    const u16* __restrict__ Vth, const u16* __restrict__ Vtl,
    const float* __restrict__ RK, const float* __restrict__ RV,
    const float* __restrict__ AM, const unsigned char* __restrict__ PM,
    u16* __restrict__ E, float* __restrict__ Lp, float* __restrict__ Accp)
{
  const int qt = blockIdx.x, b = blockIdx.y, slab = blockIdx.z;
  const int q0 = qt * 16, kbase = slab * 512;
  const int t = threadIdx.x, lane = t & 63, w = t >> 6;
  const int l15 = lane & 15, lg = lane >> 4;

  __shared__ __align__(16) float S_rel[16 * 16 * 17];   // [q][h][16k + 1 pad]
  __shared__ __align__(16) float mask_s[16 * 33];       // [q][32k + 1 pad]
  __shared__ __align__(16) u16 e_hi[16 * 648];          // [q][h*40 + kk], q-stride 648
  __shared__ __align__(16) u16 e_lo[16 * 648];

  f32x4 accV[2][4], accR[2][4];
#pragma unroll
  for (int a = 0; a < 2; ++a)
#pragma unroll
    for (int c = 0; c < 4; ++c) {
      accV[a][c] = (f32x4){0.f, 0.f, 0.f, 0.f};
      accR[a][c] = (f32x4){0.f, 0.f, 0.f, 0.f};
    }
  float lreg[2][4] = {{0.f, 0.f, 0.f, 0.f}, {0.f, 0.f, 0.f, 0.f}};

  for (int kt = 0; kt < 16; ++kt) {
    const int k0 = kbase + kt * 32;
    { // stage additive mask + padding for this 32-k tile
      const int mq = t >> 5, mk = t & 31;
      float am = AM[((size_t)b * 1024 + (q0 + mq)) * 1024 + (k0 + mk)];
      mask_s[mq * 33 + mk] = PM[b * 1024 + k0 + mk] ? -INFINITY : am;
    }
#pragma unroll
    for (int nt = 0; nt < 2; ++nt) {
      // ---- relation-k phase: per query, M=heads ----
#pragma unroll
      for (int qs = 0; qs < 2; ++qs) {
        const int q = w * 2 + qs;
        size_t rb = (((size_t)b * 1024 + (q0 + q)) * 1024 + (size_t)(k0 + nt * 16 + l15)) * 64 + 8 * lg;
        float4 f00 = *(const float4*)(RK + rb);
        float4 f01 = *(const float4*)(RK + rb + 4);
        float4 f10 = *(const float4*)(RK + rb + 32);
        float4 f11 = *(const float4*)(RK + rb + 36);
        bf16x8 bh0, bl0, bh1, bl1;
        cvt8(f00, f01, bh0, bl0);
        cvt8(f10, f11, bh1, bl1);
        size_t qb = ((size_t)(b * 16 + l15) * 1024 + (q0 + q)) * 64 + 8 * lg;
        bf16x8 a0h = *(const bf16x8*)(Qh + qb);
        bf16x8 a1h = *(const bf16x8*)(Qh + qb + 32);
        bf16x8 a0l = *(const bf16x8*)(Ql + qb);
        bf16x8 a1l = *(const bf16x8*)(Ql + qb + 32);
        f32x4 c = (f32x4){0.f, 0.f, 0.f, 0.f};
        c = MFMA16(a0h, bh0, c); c = MFMA16(a1h, bh1, c);
        c = MFMA16(a0h, bl0, c); c = MFMA16(a1h, bl1, c);
        c = MFMA16(a0l, bh0, c); c = MFMA16(a1l, bh1, c);
#pragma unroll
        for (int r = 0; r < 4; ++r)
          S_rel[(q * 16 + lg * 4 + r) * 17 + l15] = c[r];
      }
      __syncthreads();
      // ---- QK^T phase + exp epilogue: per head, M=queries ----
#pragma unroll
      for (int hs = 0; hs < 2; ++hs) {
        const int h = w * 2 + hs;
        size_t qb = ((size_t)(b * 16 + h) * 1024 + (q0 + l15)) * 64 + 8 * lg;
        bf16x8 a0h = *(const bf16x8*)(Qh + qb);
        bf16x8 a1h = *(const bf16x8*)(Qh + qb + 32);
        bf16x8 a0l = *(const bf16x8*)(Ql + qb);
        bf16x8 a1l = *(const bf16x8*)(Ql + qb + 32);
        size_t kb = ((size_t)(b * 16 + h) * 1024 + (size_t)(k0 + nt * 16 + l15)) * 64 + 8 * lg;
        bf16x8 b0h = *(const bf16x8*)(Kh + kb);
        bf16x8 b1h = *(const bf16x8*)(Kh + kb + 32);
        bf16x8 b0l = *(const bf16x8*)(Kl + kb);
        bf16x8 b1l = *(const bf16x8*)(Kl + kb + 32);
        f32x4 c = (f32x4){0.f, 0.f, 0.f, 0.f};
        c = MFMA16(a0h, b0h, c); c = MFMA16(a1h, b1h, c);
        c = MFMA16(a0h, b0l, c); c = MFMA16(a1h, b1l, c);
        c = MFMA16(a0l, b0h, c); c = MFMA16(a1l, b1h, c);
#pragma unroll
        for (int r = 0; r < 4; ++r) {
          const int qr = lg * 4 + r, kk = nt * 16 + l15;
          float sv = c[r] + S_rel[(qr * 16 + h) * 17 + l15] + mask_s[qr * 33 + kk];
          float e = __expf(sv);           // no-max softmax numerator (|S| small, f32-safe)
          lreg[hs][r] += e;
          u16 eh, el; split2(e, eh, el);
          e_hi[qr * 648 + h * 40 + kk] = eh;
          e_lo[qr * 648 + h * 40 + kk] = el;
          E[(((size_t)b * 1024 + (q0 + qr)) * 16 + h) * 1024 + (k0 + kk)] = eh;
        }
      }
      __syncthreads();
    }
    // ---- PV: V part (per head, M=queries), B = V^T contiguous ----
#pragma unroll
    for (int hs = 0; hs < 2; ++hs) {
      const int h = w * 2 + hs;
      bf16x8 aeh = *(const bf16x8*)&e_hi[l15 * 648 + h * 40 + 8 * lg];
      bf16x8 ael = *(const bf16x8*)&e_lo[l15 * 648 + h * 40 + 8 * lg];
#pragma unroll
      for (int ntd = 0; ntd < 4; ++ntd) {
        size_t vb = ((size_t)(b * 16 + h) * 64 + (ntd * 16 + l15)) * 1024 + (size_t)(k0 + 8 * lg);
        bf16x8 bvh = *(const bf16x8*)(Vth + vb);
        bf16x8 bvl = *(const bf16x8*)(Vtl + vb);
        f32x4 a = accV[hs][ntd];
        a = MFMA16(aeh, bvh, a);
        a = MFMA16(aeh, bvl, a);
        a = MFMA16(ael, bvh, a);
        accV[hs][ntd] = a;
      }
    }
    // ---- PV: relations_v part (per query, M=heads), B loaded strided f32 ----
#pragma unroll
    for (int qs = 0; qs < 2; ++qs) {
      const int q = w * 2 + qs;
      bf16x8 aeh = *(const bf16x8*)&e_hi[q * 648 + l15 * 40 + 8 * lg];
      bf16x8 ael = *(const bf16x8*)&e_lo[q * 648 + l15 * 40 + 8 * lg];
#pragma unroll
      for (int ntd = 0; ntd < 4; ++ntd) {
        size_t rb = (((size_t)b * 1024 + (q0 + q)) * 1024 + (size_t)(k0 + 8 * lg)) * 64 + (ntd * 16 + l15);
        float v[8];
#pragma unroll
        for (int jj = 0; jj < 8; ++jj) v[jj] = RV[rb + (size_t)jj * 64];
        bf16x8 bh, bl;
#pragma unroll
        for (int jj = 0; jj < 8; ++jj) {
          u16 x, y; split2(v[jj], x, y);
          bh[jj] = (short)x; bl[jj] = (short)y;
        }
        f32x4 a = accR[qs][ntd];
        a = MFMA16(aeh, bh, a);
        a = MFMA16(aeh, bl, a);
        a = MFMA16(ael, bh, a);
        accR[qs][ntd] = a;
      }
    }
    __syncthreads();
  }
  // ---- per-head partial softmax denominators ----
#pragma unroll
  for (int hs = 0; hs < 2; ++hs) {
    const int h = w * 2 + hs;
#pragma unroll
    for (int r = 0; r < 4; ++r) {
      float v = lreg[hs][r];
      v += __shfl_xor(v, 1, 16);
      v += __shfl_xor(v, 2, 16);
      v += __shfl_xor(v, 4, 16);
      v += __shfl_xor(v, 8, 16);
      if (l15 == 0)
        Lp[((size_t)(slab * 2 + b) * 16 + h) * 1024 + (q0 + lg * 4 + r)] = v;
    }
  }
  // ---- combine accV (rows=q) + accR (rows=h) through LDS, write partial out ----
#pragma unroll
  for (int p = 0; p < 4; ++p) {
    __syncthreads();
#pragma unroll
    for (int hs = 0; hs < 2; ++hs) {
      const int h = w * 2 + hs;
      f32x4 a = accV[hs][p];
#pragma unroll
      for (int r = 0; r < 4; ++r)
        S_rel[((lg * 4 + r) * 16 + h) * 17 + l15] = a[r];
    }
    __syncthreads();
#pragma unroll
    for (int qs = 0; qs < 2; ++qs) {
      const int q = w * 2 + qs;
      f32x4 a = accR[qs][p];
#pragma unroll
      for (int r = 0; r < 4; ++r)
        S_rel[(q * 16 + lg * 4 + r) * 17 + l15] += a[r];
    }
    __syncthreads();
    {
      const int q = t >> 5, h = (t >> 1) & 15, d8 = (t & 1) * 8;
      float o[8];
#pragma unroll
      for (int u = 0; u < 8; ++u) o[u] = S_rel[(q * 16 + h) * 17 + d8 + u];
      size_t ob = ((size_t)(slab * 2 + b) * 1024 + (q0 + q)) * 1024 + h * 64 + p * 16 + d8;
      float4 v0 = {o[0], o[1], o[2], o[3]};
      float4 v1 = {o[4], o[5], o[6], o[7]};
      *(float4*)(Accp + ob) = v0;
      *(float4*)(Accp + ob + 4) = v1;
    }
  }
}

// ---------------------------------------------------------------------------
// 4) combine k-halves, normalize by l, split to bf16 for O-proj input
// ---------------------------------------------------------------------------
__global__ __launch_bounds__(256) void k_combine(
    const float* __restrict__ Accp, const float* __restrict__ Lp,
    u16* __restrict__ Xoh, u16* __restrict__ Xol)
{
  size_t idx = ((size_t)blockIdx.x * 256 + threadIdx.x) * 4;
  const int e = (int)(idx & 1023);
  const int n = (int)(idx >> 10);
  const int b = n >> 10, q = n & 1023, h = e >> 6;
  float4 a0 = *(const float4*)(Accp + (size_t)b * 1048576 + (size_t)q * 1024 + e);
  float4 a1 = *(const float4*)(Accp + (size_t)(2 + b) * 1048576 + (size_t)q * 1024 + e);
  float l = Lp[((size_t)b * 16 + h) * 1024 + q] + Lp[((size_t)(2 + b) * 16 + h) * 1024 + q];
  float inv = 1.0f / l;
  ushort4 H, L; u16 x, y;
  split2((a0.x + a1.x) * inv, x, y); H.x = x; L.x = y;
  split2((a0.y + a1.y) * inv, x, y); H.y = x; L.y = y;
  split2((a0.z + a1.z) * inv, x, y); H.z = x; L.z = y;
  split2((a0.w + a1.w) * inv, x, y); H.w = x; L.w = y;
  *(ushort4*)(Xoh + idx) = H;
  *(ushort4*)(Xol + idx) = L;
}

// ---------------------------------------------------------------------------
// 5) attn_weights_avg = sum_h E[b,q,h,k] / l[b,h,q] / 16
// ---------------------------------------------------------------------------
__global__ __launch_bounds__(256) void k_pavg(
    const u16* __restrict__ E, const float* __restrict__ Lp, float* __restrict__ out)
{
  const int q = blockIdx.x, b = blockIdx.y, t = threadIdx.x;
  __shared__ float inv[16];
  if (t < 16) {
    float l = Lp[((size_t)b * 16 + t) * 1024 + q] + Lp[((size_t)(2 + b) * 16 + t) * 1024 + q];
    inv[t] = 1.0f / (16.0f * l);
  }
  __syncthreads();
  const int kb = t * 4;
  float4 s = {0.f, 0.f, 0.f, 0.f};
  const u16* Eb = E + ((size_t)b * 1024 + q) * 16 * 1024;
#pragma unroll
  for (int h = 0; h < 16; ++h) {
    ushort4 ev = *(const ushort4*)(Eb + (size_t)h * 1024 + kb);
    float iv = inv[h];
    s.x += bf2f(ev.x) * iv;
    s.y += bf2f(ev.y) * iv;
    s.z += bf2f(ev.z) * iv;
    s.w += bf2f(ev.w) * iv;
  }
  *(float4*)(out + 2097152 + ((size_t)b * 1024 + q) * 1024 + kb) = s;
}

// ---------------------------------------------------------------------------
extern "C" void kernel_launch(void* const* d_in, const int* in_sizes, int n_in,
                              void* d_out, int out_size, void* d_ws, size_t ws_size,
                              hipStream_t stream) {
  const float* query = (const float*)d_in[0];
  const float* key   = (const float*)d_in[1];
  const float* value = (const float*)d_in[2];
  const float* relk  = (const float*)d_in[3];
  const float* relv  = (const float*)d_in[4];
  const float* amask = (const float*)d_in[5];
  const unsigned char* pmask = (const unsigned char*)d_in[6];
  const float* qw = (const float*)d_in[7];
  const float* qb = (const float*)d_in[8];
  const float* kw = (const float*)d_in[9];
  const float* kb = (const float*)d_in[10];
  const float* vw = (const float*)d_in[11];
  const float* vb = (const float*)d_in[12];
  const float* ow = (const float*)d_in[13];
  const float* ob = (const float*)d_in[14];
  float* out = (float*)d_out;

  char* ws = (char*)d_ws;
  size_t off = 0;
  auto alloc = [&](size_t bytes) -> void* {
    void* p = ws + off;
    off += (bytes + 255) & ~(size_t)255;
    return p;
  };
  u16* Xhi = (u16*)alloc((size_t)3 * 2097152 * 2);
  u16* Xlo = (u16*)alloc((size_t)3 * 2097152 * 2);
  u16* Whi = (u16*)alloc((size_t)4 * 1048576 * 2);
  u16* Wlo = (u16*)alloc((size_t)4 * 1048576 * 2);
  u16* Qhi = (u16*)alloc((size_t)2097152 * 2);
  u16* Qlo = (u16*)alloc((size_t)2097152 * 2);
  u16* Khi = (u16*)alloc((size_t)2097152 * 2);
  u16* Klo = (u16*)alloc((size_t)2097152 * 2);
  u16* Vth = (u16*)alloc((size_t)2097152 * 2);
  u16* Vtl = (u16*)alloc((size_t)2097152 * 2);
  u16* Xoh = (u16*)alloc((size_t)2097152 * 2);
  u16* Xol = (u16*)alloc((size_t)2097152 * 2);
  u16* E   = (u16*)alloc((size_t)33554432 * 2);        // [b][q][h][k] bf16
  float* Lp   = (float*)alloc((size_t)4 * 16 * 1024 * 4);   // [slab*2+b][h][q]
  float* Accp = (float*)alloc((size_t)4 * 1048576 * 4);     // [slab*2+b][q][e]

  k_split<<<dim3(2048, 7), 256, 0, stream>>>(query, key, value, qw, kw, vw, ow,
                                             Xhi, Xlo, Whi, Wlo);
  k_gemm<0><<<dim3(16, 8, 3), 256, 0, stream>>>(Xhi, Xlo, Whi, Wlo, qb, kb, vb,
                                                Qhi, Qlo, Khi, Klo, Vth, Vtl, nullptr);
  k_attn<<<dim3(64, 2, 2), 512, 0, stream>>>(Qhi, Qlo, Khi, Klo, Vth, Vtl,
                                             relk, relv, amask, pmask, E, Lp, Accp);
  k_combine<<<dim3(2048), 256, 0, stream>>>(Accp, Lp, Xoh, Xol);
  k_gemm<1><<<dim3(16, 8, 1), 256, 0, stream>>>(Xoh, Xol, Whi + (size_t)3 * 1048576, Wlo + (size_t)3 * 1048576,
                                                ob, ob, ob,
                                                nullptr, nullptr, nullptr, nullptr, nullptr, nullptr, out);
  k_pavg<<<dim3(1024, 2), 256, 0, stream>>>(E, Lp, out);
}